// Round 1
// 107.348 us; speedup vs baseline: 1.0072x; 1.0072x over previous
//
#include <hip/hip_runtime.h>

typedef __bf16 bf16_t;
typedef __bf16 bf16x8 __attribute__((ext_vector_type(8)));
typedef float f32x4 __attribute__((ext_vector_type(4)));

#define L2E 1.44269504088896340736f
#define LN2 0.69314718055994530942f

#define N 2048
#define M 16
#define D 128
#define NM (N * M)  // 32768
#define NCG 16      // col-groups in main_kernel

// ---------------------------------------------------------------------------
// Kernel 1: centroids, bf16 casts, self-similarity terms.
// grid = N blocks, 128 threads (one thread per d).
// Also zeroes the scalar output (replaces a dedicated memset dispatch).
// ---------------------------------------------------------------------------
__global__ __launch_bounds__(128) void prep_kernel(
    const float* __restrict__ x, bf16_t* __restrict__ xb,
    bf16_t* __restrict__ cb, float* __restrict__ dnn,
    float* __restrict__ diag, float* __restrict__ out) {
  int n = blockIdx.x, t = threadIdx.x;
  if (n == 0 && t == 0) *out = 0.f;  // runs before finish_kernel's atomics
  __shared__ float sc[D];
  const float* xr = x + (size_t)n * (M * D);
  float xv[M];
  float c = 0.f;
#pragma unroll
  for (int m = 0; m < M; ++m) {
    xv[m] = xr[m * D + t];
    c += xv[m];
  }
  c *= (1.f / M);
  sc[t] = c;
  cb[n * D + t] = (bf16_t)c;
#pragma unroll
  for (int m = 0; m < M; ++m)
    xb[(size_t)n * (M * D) + m * D + t] = (bf16_t)xv[m];
  __syncthreads();
  // phase 2: per-(n,m) dots: dnn = x.c, xx = x.x. 8 threads per m.
  // xr re-read hits L1 (8 KB row, just touched).
  int m = t >> 3, j = t & 7;
  float p = 0.f, q = 0.f;
#pragma unroll
  for (int i = 0; i < 16; ++i) {
    int d = j * 16 + i;
    float xd = xr[m * D + d];
    float cd = sc[d];
    p += xd * cd;
    q += xd * xd;
  }
  p += __shfl_xor(p, 1); p += __shfl_xor(p, 2); p += __shfl_xor(p, 4);
  q += __shfl_xor(q, 1); q += __shfl_xor(q, 2); q += __shfl_xor(q, 4);
  if (j == 0) {
    dnn[n * M + m] = p;
    diag[n * M + m] = (16.f * p - q) * (1.f / 15.f);
  }
}

// ---------------------------------------------------------------------------
// Kernel 2: fused GEMM + exp2 row-sum.
// grid = 2048 blocks (128 row-groups x 16 col-groups), 256 threads (4 waves).
// Each wave: 64 rows (4x 16-row MFMA tiles) x 128 cols (block col-group).
// B col-group staged once into padded LDS -> single barrier per block.
// Partial row-sums are written non-atomically: each (row, col-group) partial
// is produced by exactly one wave, so rowsum_p[cg][row] = plain store.
// No zero-init of the buffer required.
// ---------------------------------------------------------------------------
#define TSTR 136  // 128 + 8 bf16 pad: keeps 16B alignment, kills bank conflicts

__global__ __launch_bounds__(256) void main_kernel(
    const bf16_t* __restrict__ xb, const bf16_t* __restrict__ cb,
    const float* __restrict__ wp, const float* __restrict__ bp,
    float* __restrict__ rowsum_p) {
  __shared__ bf16_t tile[128 * TSTR];
  int t = threadIdx.x;
  int rg = blockIdx.x >> 4;
  int cg = blockIdx.x & 15;
  int R0 = rg * 256, C0 = cg * 128;

  // stage 128 cols x 128 k of cb into LDS (coalesced 16B per lane)
#pragma unroll
  for (int i = 0; i < 8; ++i) {
    int col = i * 16 + (t >> 4);
    int k = (t & 15) * 8;
    uint4 v = *(const uint4*)(cb + (size_t)(C0 + col) * D + k);
    *(uint4*)(&tile[col * TSTR + k]) = v;
  }

  int w = t >> 6, lane = t & 63;
  int la = lane & 15, lb = lane >> 4;
  int rowbase = R0 + w * 64;

  // A fragments: 4 row-tiles x 4 K-chunks, resident in VGPRs
  bf16x8 a[4][4];
#pragma unroll
  for (int rt = 0; rt < 4; ++rt)
#pragma unroll
    for (int kc = 0; kc < 4; ++kc)
      a[rt][kc] = *(const bf16x8*)(xb + (size_t)(rowbase + rt * 16 + la) * D +
                                   kc * 32 + lb * 8);
  __syncthreads();

  float wv = wp[0], bv = bp[0];
  float wsc = wv * L2E, bsc = bv * L2E;
  float sums[4][4];
#pragma unroll
  for (int rt = 0; rt < 4; ++rt)
#pragma unroll
    for (int r = 0; r < 4; ++r) sums[rt][r] = 0.f;

#pragma unroll
  for (int cs = 0; cs < 8; ++cs) {
    bf16x8 bfr[4];
    const bf16_t* b0 = &tile[(cs * 16 + la) * TSTR + lb * 8];
#pragma unroll
    for (int kc = 0; kc < 4; ++kc) bfr[kc] = *(const bf16x8*)(b0 + kc * 32);
#pragma unroll
    for (int rt = 0; rt < 4; ++rt) {
      f32x4 acc = {0.f, 0.f, 0.f, 0.f};
#pragma unroll
      for (int kc = 0; kc < 4; ++kc)
        acc = __builtin_amdgcn_mfma_f32_16x16x32_bf16(a[rt][kc], bfr[kc], acc,
                                                      0, 0, 0);
#pragma unroll
      for (int r = 0; r < 4; ++r)
        sums[rt][r] += __builtin_amdgcn_exp2f(acc[r] * wsc + bsc);
    }
  }

  // reduce across the 16 lanes holding the same row (la dimension), then one
  // plain store per row per col-group (no atomics, no memset dependency).
  float* rp = rowsum_p + (size_t)cg * NM;
#pragma unroll
  for (int rt = 0; rt < 4; ++rt)
#pragma unroll
    for (int r = 0; r < 4; ++r) {
      float v = sums[rt][r];
      v += __shfl_xor(v, 1); v += __shfl_xor(v, 2);
      v += __shfl_xor(v, 4); v += __shfl_xor(v, 8);
      if (la == 0)
        rp[rowbase + rt * 16 + lb * 4 + r] = v;
    }
}

// ---------------------------------------------------------------------------
// Kernel 3: sum 16 partials, self-term correction + log + mean.
// grid = 128 x 256.
// ---------------------------------------------------------------------------
__global__ __launch_bounds__(256) void finish_kernel(
    const float* __restrict__ rowsum_p, const float* __restrict__ dnn,
    const float* __restrict__ diag, const float* __restrict__ wp,
    const float* __restrict__ bp, float* __restrict__ out) {
  int i = blockIdx.x * 256 + threadIdx.x;
  float wv = wp[0], bv = bp[0];
  float S0 = 0.f;
#pragma unroll
  for (int k = 0; k < NCG; ++k) S0 += rowsum_p[(size_t)k * NM + i];
  float tnn = (wv * dnn[i] + bv) * L2E;
  float sself = wv * diag[i] + bv;
  float S = S0 - __builtin_amdgcn_exp2f(tnn) +
            __builtin_amdgcn_exp2f(sself * L2E);
  float lr = __builtin_amdgcn_logf(S) * LN2 - sself;
#pragma unroll
  for (int off = 1; off < 64; off <<= 1) lr += __shfl_xor(lr, off);
  __shared__ float red[4];
  int lane = threadIdx.x & 63, wid = threadIdx.x >> 6;
  if (lane == 0) red[wid] = lr;
  __syncthreads();
  if (threadIdx.x == 0)
    atomicAdd(out, (red[0] + red[1] + red[2] + red[3]) * (1.f / NM));
}

extern "C" void kernel_launch(void* const* d_in, const int* in_sizes, int n_in,
                              void* d_out, int out_size, void* d_ws,
                              size_t ws_size, hipStream_t stream) {
  (void)in_sizes; (void)n_in; (void)out_size; (void)ws_size;
  const float* x = (const float*)d_in[0];
  const float* wp = (const float*)d_in[1];
  const float* bp = (const float*)d_in[2];
  float* out = (float*)d_out;

  char* ws = (char*)d_ws;
  bf16_t* xb = (bf16_t*)ws;                      // 32768*128*2 = 8388608 B
  bf16_t* cb = (bf16_t*)(ws + 8388608);          // 2048*128*2  = 524288 B
  float* dnn = (float*)(ws + 8912896);           // 32768*4     = 131072 B
  float* diag = (float*)(ws + 9043968);          // 32768*4     = 131072 B
  float* rowsum_p = (float*)(ws + 9175040);      // 16*32768*4  = 2097152 B

  prep_kernel<<<N, 128, 0, stream>>>(x, xb, cb, dnn, diag, out);
  main_kernel<<<2048, 256, 0, stream>>>(xb, cb, wp, bp, rowsum_p);
  finish_kernel<<<NM / 256, 256, 0, stream>>>(rowsum_p, dnn, diag, wp, bp,
                                              out);
}

// Round 2
// 96.885 us; speedup vs baseline: 1.1160x; 1.1080x over previous
//
#include <hip/hip_runtime.h>

typedef float f32x4 __attribute__((ext_vector_type(4)));
typedef int i32x8 __attribute__((ext_vector_type(8)));

#define L2E 1.44269504088896340736f
#define LN2 0.69314718055994530942f

#define N 2048
#define M 16
#define D 128
#define NM (N * M)  // 32768
#define NCG 16      // col-groups in main_kernel

// fp32 -> OCP e4m3 (single byte) via HW pack-convert.
__device__ __forceinline__ unsigned char f32_to_f8(float v) {
  return (unsigned char)(__builtin_amdgcn_cvt_pk_fp8_f32(v, v, 0, false) &
                         0xff);
}

// ---------------------------------------------------------------------------
// Kernel 1: centroids, fp8 casts, leave-one-out self-similarity.
// grid = N blocks, 128 threads (one thread per d).
// Also zeroes the scalar output (no dedicated memset dispatch).
// ---------------------------------------------------------------------------
__global__ __launch_bounds__(128) void prep_kernel(
    const float* __restrict__ x, unsigned char* __restrict__ xb8,
    unsigned char* __restrict__ cb8, float* __restrict__ diag,
    float* __restrict__ out) {
  int n = blockIdx.x, t = threadIdx.x;
  if (n == 0 && t == 0) *out = 0.f;  // runs before finish_kernel's atomics
  __shared__ float sc[D];
  const float* xr = x + (size_t)n * (M * D);
  float xv[M];
  float c = 0.f;
#pragma unroll
  for (int m = 0; m < M; ++m) {
    xv[m] = xr[m * D + t];
    c += xv[m];
  }
  c *= (1.f / M);
  sc[t] = c;
  cb8[n * D + t] = f32_to_f8(c);
#pragma unroll
  for (int m = 0; m < M; ++m)
    xb8[(size_t)(n * M + m) * D + t] = f32_to_f8(xv[m]);
  __syncthreads();
  // phase 2: per-(n,m) dots in fp32: p = x.c, q = x.x. 8 threads per m.
  int m = t >> 3, j = t & 7;
  float p = 0.f, q = 0.f;
#pragma unroll
  for (int i = 0; i < 16; ++i) {
    int d = j * 16 + i;
    float xd = xr[m * D + d];
    float cd = sc[d];
    p += xd * cd;
    q += xd * xd;
  }
  p += __shfl_xor(p, 1); p += __shfl_xor(p, 2); p += __shfl_xor(p, 4);
  q += __shfl_xor(q, 1); q += __shfl_xor(q, 2); q += __shfl_xor(q, 4);
  if (j == 0) diag[n * M + m] = (16.f * p - q) * (1.f / 15.f);
}

// ---------------------------------------------------------------------------
// Kernel 2: fused fp8 GEMM (MX-scaled, unit scales, K=128 per MFMA) +
// exp2 row-sum, with the self column masked out (fp32-exact self term is
// re-added in finish_kernel -> no fp8 error on the dominant term).
// grid = 2048 blocks (128 row-groups x 16 col-groups), 256 threads (4 waves).
// Each wave: 64 rows (4x 16-row tiles) x 128 cols; ONE mfma per 16x16 tile.
// ---------------------------------------------------------------------------
#define TS 144  // 128 + 16 byte pad: same bank-spread class as bf16's 272

__global__ __launch_bounds__(256) void main_kernel(
    const unsigned char* __restrict__ xb8,
    const unsigned char* __restrict__ cb8, const float* __restrict__ wp,
    const float* __restrict__ bp, float* __restrict__ rowsum_p) {
  __shared__ uint4 tileq[128 * TS / 16];
  unsigned char* tile = (unsigned char*)tileq;
  int t = threadIdx.x;
  int rg = blockIdx.x >> 4;
  int cg = blockIdx.x & 15;
  int R0 = rg * 256, C0 = cg * 128;

  // stage 128 cols x 128 k of cb8 (16 KB) into LDS, 64 B per thread
#pragma unroll
  for (int i = 0; i < 4; ++i) {
    int col = i * 32 + (t >> 3);
    int k = (t & 7) * 16;
    *(uint4*)(tile + col * TS + k) =
        *(const uint4*)(cb8 + (size_t)(C0 + col) * D + k);
  }

  int w = t >> 6, lane = t & 63;
  int la = lane & 15, lb = lane >> 4;
  int rowbase = R0 + w * 64;

  // A fragments: 4 row-tiles, 32 B (full K=128) per lane, resident in VGPRs
  i32x8 a[4];
#pragma unroll
  for (int rt = 0; rt < 4; ++rt) {
    const unsigned char* ap =
        xb8 + (size_t)(rowbase + rt * 16 + la) * D + lb * 32;
    uint4 a0 = *(const uint4*)(ap);
    uint4 a1 = *(const uint4*)(ap + 16);
    a[rt] = (i32x8){(int)a0.x, (int)a0.y, (int)a0.z, (int)a0.w,
                    (int)a1.x, (int)a1.y, (int)a1.z, (int)a1.w};
  }
  __syncthreads();

  float wv = wp[0], bv = bp[0];
  float wsc = wv * L2E, bsc = bv * L2E;
  // self column for rows of this rg lives in cg == rg>>3, subtile cs == rg&7,
  // at la == 4*w + rt (each 16-row tile is exactly one speaker n).
  int selfcs = (cg == (rg >> 3)) ? (rg & 7) : -1;

  float sums[4][4];
#pragma unroll
  for (int rt = 0; rt < 4; ++rt)
#pragma unroll
    for (int r = 0; r < 4; ++r) sums[rt][r] = 0.f;

#pragma unroll
  for (int cs = 0; cs < 8; ++cs) {
    const unsigned char* bp8 = tile + (cs * 16 + la) * TS + lb * 32;
    uint4 b0 = *(const uint4*)(bp8);
    uint4 b1 = *(const uint4*)(bp8 + 16);
    i32x8 bf = (i32x8){(int)b0.x, (int)b0.y, (int)b0.z, (int)b0.w,
                       (int)b1.x, (int)b1.y, (int)b1.z, (int)b1.w};
#pragma unroll
    for (int rt = 0; rt < 4; ++rt) {
      f32x4 acc = {0.f, 0.f, 0.f, 0.f};
      acc = __builtin_amdgcn_mfma_scale_f32_16x16x128_f8f6f4(
          a[rt], bf, acc, 0, 0, 0, 0x7f7f7f7f, 0, 0x7f7f7f7f);
      bool notself = !(cs == selfcs && la == ((w << 2) | rt));
#pragma unroll
      for (int r = 0; r < 4; ++r) {
        float e = __builtin_amdgcn_exp2f(acc[r] * wsc + bsc);
        sums[rt][r] += notself ? e : 0.f;
      }
    }
  }

  // reduce across the 16 lanes holding the same row (la dimension), then one
  // plain store per row per col-group (no atomics, no memset dependency).
  float* rp = rowsum_p + (size_t)cg * NM;
#pragma unroll
  for (int rt = 0; rt < 4; ++rt)
#pragma unroll
    for (int r = 0; r < 4; ++r) {
      float v = sums[rt][r];
      v += __shfl_xor(v, 1); v += __shfl_xor(v, 2);
      v += __shfl_xor(v, 4); v += __shfl_xor(v, 8);
      if (la == 0)
        rp[rowbase + rt * 16 + lb * 4 + r] = v;
    }
}

// ---------------------------------------------------------------------------
// Kernel 3: sum 16 partials, add fp32-exact self term, log + mean.
// grid = 128 x 256.
// ---------------------------------------------------------------------------
__global__ __launch_bounds__(256) void finish_kernel(
    const float* __restrict__ rowsum_p, const float* __restrict__ diag,
    const float* __restrict__ wp, const float* __restrict__ bp,
    float* __restrict__ out) {
  int i = blockIdx.x * 256 + threadIdx.x;
  float wv = wp[0], bv = bp[0];
  float S0 = 0.f;
#pragma unroll
  for (int k = 0; k < NCG; ++k) S0 += rowsum_p[(size_t)k * NM + i];
  float sself = wv * diag[i] + bv;
  float S = S0 + __builtin_amdgcn_exp2f(sself * L2E);
  float lr = __builtin_amdgcn_logf(S) * LN2 - sself;
#pragma unroll
  for (int off = 1; off < 64; off <<= 1) lr += __shfl_xor(lr, off);
  __shared__ float red[4];
  int lane = threadIdx.x & 63, wid = threadIdx.x >> 6;
  if (lane == 0) red[wid] = lr;
  __syncthreads();
  if (threadIdx.x == 0)
    atomicAdd(out, (red[0] + red[1] + red[2] + red[3]) * (1.f / NM));
}

extern "C" void kernel_launch(void* const* d_in, const int* in_sizes, int n_in,
                              void* d_out, int out_size, void* d_ws,
                              size_t ws_size, hipStream_t stream) {
  (void)in_sizes; (void)n_in; (void)out_size; (void)ws_size;
  const float* x = (const float*)d_in[0];
  const float* wp = (const float*)d_in[1];
  const float* bp = (const float*)d_in[2];
  float* out = (float*)d_out;

  char* ws = (char*)d_ws;
  unsigned char* xb8 = (unsigned char*)ws;       // 32768*128 = 4194304 B
  unsigned char* cb8 = (unsigned char*)(ws + 4194304);  // 2048*128 = 262144 B
  float* diag = (float*)(ws + 4456448);          // 32768*4    = 131072 B
  float* rowsum_p = (float*)(ws + 4587520);      // 16*32768*4 = 2097152 B

  prep_kernel<<<N, 128, 0, stream>>>(x, xb8, cb8, diag, out);
  main_kernel<<<2048, 256, 0, stream>>>(xb8, cb8, wp, bp, rowsum_p);
  finish_kernel<<<NM / 256, 256, 0, stream>>>(rowsum_p, diag, wp, bp, out);
}